// Round 4
// baseline (218.873 us; speedup 1.0000x reference)
//
#include <hip/hip_runtime.h>

// Pixel-unshuffle 2x2 (space-to-depth), fp32.
// in : [32, 1, 2048, 2048]  out : [32, 4, 1024, 1024]
// out[b][2*(h&1) + (w&1)][h/2][w/2] = in[b][0][h][w]
//
// R4: fully-coalesced loads. Lane i loads in4[base+i] (contiguous 1KB per
// load instruction, vs 32B-stride in R3 which doubled the L2 request rate).
// Lane pair (2j,2j+1) jointly holds 8 consecutive floats; a single
// __shfl_xor(.,1) exchange (DPP quad-perm) gives the even lane the
// even-column float4 and the odd lane the odd-column float4. Stores are two
// contiguous 512B segments per instruction (even lanes -> plane c, odd ->
// plane c+1), fully line-utilized. nt on both sides (touch-once streams).

typedef float f32x4 __attribute__((ext_vector_type(4)));

__device__ __forceinline__ void proc_item(
    int t, int e, f32x4 v, f32x4* __restrict__ out4) {
    // Exchange with partner lane (lane^1). Even lane sends (y,w), receives
    // partner's (x,z); odd lane sends (x,z), receives partner's (y,w).
    const float send1 = e ? v.x : v.y;
    const float send2 = e ? v.z : v.w;
    const float r1 = __shfl_xor(send1, 1, 64);
    const float r2 = __shfl_xor(send2, 1, 64);

    f32x4 o;
    o.x = e ? r1 : v.x;
    o.y = e ? r2 : v.z;
    o.z = e ? v.y : r1;
    o.w = e ? v.w : r2;

    // Pair index p owns input floats 8p..8p+7 -> output float4 col p&255.
    const int p    = t >> 1;
    const int prow = p & 255;   // 256 output float4 per row pair
    const int row  = p >> 8;    // b*2048 + h
    const int h    = row & 2047;
    const int b    = row >> 11;
    const int i    = h >> 1;
    const int c    = ((h & 1) << 1) + e;
    // float4-unit offsets: out plane = 262144 float4, out row = 256 float4
    const int off  = (((b << 2) + c) << 18) + (i << 8) + prow;

    __builtin_nontemporal_store(o, out4 + off);
}

__global__ __launch_bounds__(256) void pixel_unshuffle_kernel(
    const f32x4* __restrict__ in4, f32x4* __restrict__ out4, int n4) {
    const int tpb  = 256;
    const int span = gridDim.x * tpb * 4;
    const int e    = threadIdx.x & 1;
    for (int base = blockIdx.x * tpb * 4 + threadIdx.x; base < n4;
         base += span) {
        const int t0 = base;
        const int t1 = base + tpb;      // n4 % span == 0 for this shape
        const int t2 = base + 2 * tpb;
        const int t3 = base + 3 * tpb;

        // Fully-coalesced: lane i -> in4[wave_base + i], 1KB/instr.
        const f32x4 v0 = __builtin_nontemporal_load(in4 + t0);
        const f32x4 v1 = __builtin_nontemporal_load(in4 + t1);
        const f32x4 v2 = __builtin_nontemporal_load(in4 + t2);
        const f32x4 v3 = __builtin_nontemporal_load(in4 + t3);

        proc_item(t0, e, v0, out4);
        proc_item(t1, e, v1, out4);
        proc_item(t2, e, v2, out4);
        proc_item(t3, e, v3, out4);
    }
}

extern "C" void kernel_launch(void* const* d_in, const int* in_sizes, int n_in,
                              void* d_out, int out_size, void* d_ws, size_t ws_size,
                              hipStream_t stream) {
    const f32x4* in4 = (const f32x4*)d_in[0];
    f32x4* out4      = (f32x4*)d_out;

    const int n4    = 32 * 2048 * 2048 / 4;  // 33,554,432 float4
    const int block = 256;
    const int grid  = 2048;  // 16 sweeps of the grid-stride loop

    pixel_unshuffle_kernel<<<grid, block, 0, stream>>>(in4, out4, n4);
}

// Round 5
// 208.257 us; speedup vs baseline: 1.0510x; 1.0510x over previous
//
#include <hip/hip_runtime.h>

// Pixel-unshuffle 2x2 (space-to-depth), fp32.
// in : [32, 1, 2048, 2048]  out : [32, 4, 1024, 1024]
// out[b][2*(h&1) + (w&1)][h/2][w/2] = in[b][0][h][w]
//
// R5: dense on BOTH sides, no cross-lane ops.
//   load : lane reads ONE float4 (4 consecutive floats, one row) ->
//          64 lanes = 1KB contiguous per load instruction.
//   store: (x,z) -> float2 in plane cbase, (y,w) -> float2 in plane cbase+1,
//          both at float2-index f&511 -> 64 lanes = 512B contiguous per
//          store instruction (whole wave same plane, monotonic lane->addr).
// R4 lesson: lane-adjacent addresses MUST be contiguous; parity-split planes
// across lanes shattered store coalescing. nt hints (touch-once streams),
// 4-deep ILP (R3 win), grid 2048x256.

typedef float f32x4 __attribute__((ext_vector_type(4)));
typedef float f32x2 __attribute__((ext_vector_type(2)));

__device__ __forceinline__ void proc_item(
    int f, f32x4 v, f32x2* __restrict__ out2) {
    const int col = f & 511;    // float2-index within output row (512/row)
    const int row = f >> 9;     // b*2048 + h   (512 float4 per input row)
    const int h   = row & 2047;
    const int b   = row >> 11;
    const int i   = h >> 1;
    const int c   = (h & 1) << 1;
    // float2 units: plane = 1024*512 = 1<<19, out row = 1<<9
    const int off = (((b << 2) + c) << 19) + (i << 9) + col;

    f32x2 ev, od;
    ev.x = v.x; ev.y = v.z;
    od.x = v.y; od.y = v.w;

    __builtin_nontemporal_store(ev, out2 + off);              // plane c
    __builtin_nontemporal_store(od, out2 + off + (1 << 19));  // plane c+1
}

__global__ __launch_bounds__(256) void pixel_unshuffle_kernel(
    const f32x4* __restrict__ in4, f32x2* __restrict__ out2, int n4) {
    const int tpb  = 256;
    const int span = gridDim.x * tpb * 4;
    for (int base = blockIdx.x * tpb * 4 + threadIdx.x; base < n4;
         base += span) {
        const int f0 = base;
        const int f1 = base + tpb;      // n4 % span == 0 for this shape
        const int f2 = base + 2 * tpb;
        const int f3 = base + 3 * tpb;

        // Fully-dense loads: 1KB contiguous per instruction.
        const f32x4 v0 = __builtin_nontemporal_load(in4 + f0);
        const f32x4 v1 = __builtin_nontemporal_load(in4 + f1);
        const f32x4 v2 = __builtin_nontemporal_load(in4 + f2);
        const f32x4 v3 = __builtin_nontemporal_load(in4 + f3);

        proc_item(f0, v0, out2);
        proc_item(f1, v1, out2);
        proc_item(f2, v2, out2);
        proc_item(f3, v3, out2);
    }
}

extern "C" void kernel_launch(void* const* d_in, const int* in_sizes, int n_in,
                              void* d_out, int out_size, void* d_ws, size_t ws_size,
                              hipStream_t stream) {
    const f32x4* in4 = (const f32x4*)d_in[0];
    f32x2* out2      = (f32x2*)d_out;

    const int n4    = 32 * 2048 * 2048 / 4;  // 33,554,432 float4
    const int block = 256;
    const int grid  = 2048;  // 16 sweeps of the grid-stride loop

    pixel_unshuffle_kernel<<<grid, block, 0, stream>>>(in4, out2, n4);
}